// Round 5
// baseline (433.066 us; speedup 1.0000x reference)
//
#include <hip/hip_runtime.h>
#include <hip/hip_bf16.h>
#include <cstdint>

typedef unsigned short ushort_t;
typedef __attribute__((ext_vector_type(8))) short short8;
typedef __attribute__((ext_vector_type(4))) float floatx4;

#define H_   16
#define DKV_ 64
#define DM_  1024
#define B_   2
#define NQ_  2048
#define NK_  2048

// fp32 -> bf16 round-to-nearest-even
__device__ __forceinline__ unsigned short f2bf(float f) {
  union { float f; unsigned int u; } v; v.f = f;
  unsigned int u = v.u;
  return (unsigned short)((u + 0x7fffu + ((u >> 16) & 1u)) >> 16);
}

// Trans ops via compiler-visible intrinsics (NOT inline asm): the backend's
// hazard recognizer must see v_exp_f32/v_rcp_f32 to insert result wait-states.
__device__ __forceinline__ float fexp2(float x) { return __builtin_amdgcn_exp2f(x); }
__device__ __forceinline__ float frcp(float x)  { return __builtin_amdgcn_rcpf(x); }

__device__ __forceinline__ floatx4 mfma16(short8 a, short8 b, floatx4 c) {
  return __builtin_amdgcn_mfma_f32_16x16x32_bf16(a, b, c, 0, 0, 0);
}

// ---------------- Projection GEMM (R2-proven):  C = X @ W + bias -> bf16 ---
// mode 0: Q scaled by log2(e)/8 -> [b,h,n,d]; mode 1: K -> [b,h,n,d];
// mode 2: V -> [b,h,d,n] (transposed for PV B-fragments)
constexpr int LDT = 40; // padded LDS row (bf16)

__global__ __launch_bounds__(256, 2) void proj_kernel(
    const float* __restrict__ Xq, const float* __restrict__ Xk, const float* __restrict__ Xv,
    const float* __restrict__ Wq, const float* __restrict__ Wk, const float* __restrict__ Wv,
    const float* __restrict__ bq, const float* __restrict__ bk, const float* __restrict__ bv,
    ushort_t* __restrict__ Qb, ushort_t* __restrict__ Kb, ushort_t* __restrict__ Vt)
{
  const int mode = blockIdx.z;
  const float* X    = (mode == 0) ? Xq : (mode == 1) ? Xk : Xv;
  const float* W    = (mode == 0) ? Wq : (mode == 1) ? Wk : Wv;
  const float* bias = (mode == 0) ? bq : (mode == 1) ? bk : bv;
  ushort_t* dst     = (mode == 0) ? Qb : (mode == 1) ? Kb : Vt;

  __shared__ ushort_t Asm[128 * LDT];
  __shared__ ushort_t Bsm[128 * LDT];

  const int tid = threadIdx.x, lane = tid & 63, wid = tid >> 6;
  const int m0 = blockIdx.y * 128, n0 = blockIdx.x * 128;
  const int c = lane & 15, g = lane >> 4;
  const int wm = wid & 1, wn = wid >> 1, mb = wm * 64, nb = wn * 64;

  floatx4 acc[4][4];
  #pragma unroll
  for (int i = 0; i < 4; i++)
    #pragma unroll
    for (int j = 0; j < 4; j++) acc[i][j] = floatx4{0.f, 0.f, 0.f, 0.f};

  const int ar = tid >> 1, ah = tid & 1;      // A staging: row, k-half
  const int bn = tid & 127, bh2 = tid >> 7;   // B staging: col n, k-half

  for (int k0 = 0; k0 < DM_; k0 += 32) {
    const floatx4* ap = (const floatx4*)(X + (size_t)(m0 + ar) * DM_ + k0 + ah * 16);
    floatx4 av0 = ap[0], av1 = ap[1], av2 = ap[2], av3 = ap[3];
    const float* wp = W + (size_t)(k0 + bh2 * 16) * 1024 + n0 + bn;
    float wv[16];
    #pragma unroll
    for (int j = 0; j < 16; j++) wv[j] = wp[j * 1024];

    short8 pa0, pa1, pb0, pb1;
    #pragma unroll
    for (int j = 0; j < 4; j++) {
      pa0[j] = (short)f2bf(av0[j]); pa0[4 + j] = (short)f2bf(av1[j]);
      pa1[j] = (short)f2bf(av2[j]); pa1[4 + j] = (short)f2bf(av3[j]);
    }
    #pragma unroll
    for (int j = 0; j < 8; j++) { pb0[j] = (short)f2bf(wv[j]); pb1[j] = (short)f2bf(wv[8 + j]); }

    __syncthreads();   // previous iter's fragment reads complete
    *(short8*)&Asm[ar * LDT + ah * 16]      = pa0;
    *(short8*)&Asm[ar * LDT + ah * 16 + 8]  = pa1;
    *(short8*)&Bsm[bn * LDT + bh2 * 16]     = pb0;
    *(short8*)&Bsm[bn * LDT + bh2 * 16 + 8] = pb1;
    __syncthreads();

    short8 af[4], bfr[4];
    #pragma unroll
    for (int i = 0; i < 4; i++) af[i]  = *(const short8*)&Asm[(mb + i * 16 + c) * LDT + g * 8];
    #pragma unroll
    for (int j = 0; j < 4; j++) bfr[j] = *(const short8*)&Bsm[(nb + j * 16 + c) * LDT + g * 8];
    #pragma unroll
    for (int i = 0; i < 4; i++)
      #pragma unroll
      for (int j = 0; j < 4; j++) acc[i][j] = mfma16(af[i], bfr[j], acc[i][j]);
  }

  // epilogue: C/D layout col=lane&15, row=(lane>>4)*4+reg
  #pragma unroll
  for (int j = 0; j < 4; j++) {
    const int col = n0 + nb + j * 16 + c;
    const float bv_ = bias[col];
    const int h = col >> 6, d = col & 63;
    #pragma unroll
    for (int i = 0; i < 4; i++) {
      #pragma unroll
      for (int r = 0; r < 4; r++) {
        const int row = m0 + mb + i * 16 + g * 4 + r;
        const int b = row >> 11, n = row & 2047;
        float v = acc[i][j][r] + bv_;
        if (mode == 0) {
          v *= 0.18033688011112042f;  // log2(e)/8 folded into Q
          dst[((size_t)(b * H_ + h) * NQ_ + n) * DKV_ + d] = f2bf(v);
        } else if (mode == 1) {
          dst[((size_t)(b * H_ + h) * NQ_ + n) * DKV_ + d] = f2bf(v);
        } else {
          dst[((size_t)(b * H_ + h) * DKV_ + d) * NK_ + n] = f2bf(v);
        }
      }
    }
  }
}

// ---------------- attn v2: no-max flash, deferred l-reduction -------------
// 1 wave = 16 q-rows; block = 64 q-rows; grid 1024 -> 4 blocks/CU.
// p = exp2(s_log2) (safe: |s_log2| <= ~10 by construction), l per-lane
// partial (reduced once at end); gate by gp; P transits LDS (C->A layout).
__global__ __launch_bounds__(256, 4) void attn_kernel(
    const ushort_t* __restrict__ Qb, const ushort_t* __restrict__ Kb,
    const ushort_t* __restrict__ Vt, const float* __restrict__ gp,
    float* __restrict__ out)
{
  __shared__ ushort_t Pl[4 * 16 * 72];   // per-wave P tile, stride 72

  const int tid = threadIdx.x, lane = tid & 63, wid = tid >> 6;
  const int c = lane & 15, g = lane >> 4;
  const int b = blockIdx.z, h = blockIdx.y;
  const int bh = b * H_ + h;
  const int qw = blockIdx.x * 64 + wid * 16;

  const ushort_t* Qp = Qb + (size_t)bh * NQ_ * DKV_;
  const ushort_t* Kp = Kb + (size_t)bh * NK_ * DKV_;
  const ushort_t* Vp = Vt + (size_t)bh * DKV_ * NK_;
  const float* gpp = gp + (size_t)b * NQ_ * NK_ + (size_t)qw * NK_;
  ushort_t* Pw = &Pl[wid * 16 * 72];

  // Q fragments (pre-scaled by log2(e)/8 in proj)
  short8 qf0 = *(const short8*)&Qp[(qw + c) * DKV_ + g * 8];
  short8 qf1 = *(const short8*)&Qp[(qw + c) * DKV_ + 32 + g * 8];

  floatx4 o[4];
  float l[4];
  #pragma unroll
  for (int jd = 0; jd < 4; jd++) o[jd] = floatx4{0.f, 0.f, 0.f, 0.f};
  #pragma unroll
  for (int r = 0; r < 4; r++) l[r] = 0.f;

  for (int k0 = 0; k0 < NK_; k0 += 64) {
    // gp gather (issued early; MFMAs hide latency)
    float gpv[4][4];
    #pragma unroll
    for (int r = 0; r < 4; r++) {
      const float* gq = gpp + (size_t)(g * 4 + r) * NK_ + k0 + c;
      #pragma unroll
      for (int jk = 0; jk < 4; jk++) gpv[jk][r] = gq[jk * 16];
    }

    // S = Q K^T (log2 domain)
    floatx4 s[4];
    #pragma unroll
    for (int jk = 0; jk < 4; jk++) s[jk] = floatx4{0.f, 0.f, 0.f, 0.f};
    #pragma unroll
    for (int jk = 0; jk < 4; jk++) {
      const ushort_t* kp = &Kp[(k0 + jk * 16 + c) * DKV_ + g * 8];
      short8 kf0 = *(const short8*)kp;
      short8 kf1 = *(const short8*)(kp + 32);
      s[jk] = mfma16(qf0, kf0, s[jk]);
      s[jk] = mfma16(qf1, kf1, s[jk]);
    }

    // p = exp2(s); accumulate per-lane l; gate and write P (C->A transpose)
    #pragma unroll
    for (int jk = 0; jk < 4; jk++)
      #pragma unroll
      for (int r = 0; r < 4; r++) {
        const float p = fexp2(s[jk][r]);
        l[r] += p;
        Pw[(g * 4 + r) * 72 + jk * 16 + c] = f2bf(p * gpv[jk][r]);
      }

    // PV: A = P rows (LDS), B = V^T contiguous
    #pragma unroll
    for (int kc = 0; kc < 2; kc++) {
      short8 af = *(const short8*)&Pw[c * 72 + kc * 32 + g * 8];
      #pragma unroll
      for (int jd = 0; jd < 4; jd++) {
        short8 vf = *(const short8*)&Vp[(jd * 16 + c) * NK_ + k0 + kc * 32 + g * 8];
        o[jd] = mfma16(af, vf, o[jd]);
      }
    }
  }

  // single l-reduction across the 16 c-lanes
  float invl[4];
  #pragma unroll
  for (int r = 0; r < 4; r++) {
    float rs = l[r];
    rs += __shfl_xor(rs, 1);
    rs += __shfl_xor(rs, 2);
    rs += __shfl_xor(rs, 4);
    rs += __shfl_xor(rs, 8);
    invl[r] = frcp(rs);
  }
  #pragma unroll
  for (int jd = 0; jd < 4; jd++)
    #pragma unroll
    for (int r = 0; r < 4; r++) {
      const int row = qw + g * 4 + r;
      out[(size_t)(b * NQ_ + row) * 1024 + h * 64 + jd * 16 + c] =
          o[jd][r] * invl[r];
    }
}

extern "C" void kernel_launch(void* const* d_in, const int* in_sizes, int n_in,
                              void* d_out, int out_size, void* d_ws, size_t ws_size,
                              hipStream_t stream) {
  const float* queries = (const float*)d_in[0];
  const float* keys    = (const float*)d_in[1];
  const float* values  = (const float*)d_in[2];
  const float* gp      = (const float*)d_in[3];
  // d_in[4] attention_mask: intentionally unused (reference discards it)
  const float* Wq = (const float*)d_in[5];
  const float* bq = (const float*)d_in[6];
  const float* Wk = (const float*)d_in[7];
  const float* bk = (const float*)d_in[8];
  const float* Wv = (const float*)d_in[9];
  const float* bv = (const float*)d_in[10];

  ushort_t* Qb = (ushort_t*)d_ws;                       // [B,H,NQ,64] bf16, pre-scaled
  ushort_t* Kb = Qb + (size_t)B_ * H_ * NQ_ * DKV_;     // [B,H,NK,64] bf16
  ushort_t* Vt = Kb + (size_t)B_ * H_ * NK_ * DKV_;     // [B,H,64,NK] bf16
  float* out = (float*)d_out;

  proj_kernel<<<dim3(8, 32, 3), 256, 0, stream>>>(
      queries, keys, values, Wq, Wk, Wv, bq, bk, bv, Qb, Kb, Vt);
  attn_kernel<<<dim3(NQ_ / 64, H_, B_), 256, 0, stream>>>(Qb, Kb, Vt, gp, out);
}

// Round 6
// 275.613 us; speedup vs baseline: 1.5713x; 1.5713x over previous
//
#include <hip/hip_runtime.h>
#include <hip/hip_bf16.h>
#include <cstdint>

typedef unsigned short ushort_t;
typedef __attribute__((ext_vector_type(8))) short short8;
typedef __attribute__((ext_vector_type(4))) float floatx4;

#define H_   16
#define DKV_ 64
#define DM_  1024
#define B_   2
#define NQ_  2048
#define NK_  2048

// fp32 -> bf16 round-to-nearest-even
__device__ __forceinline__ unsigned short f2bf(float f) {
  union { float f; unsigned int u; } v; v.f = f;
  unsigned int u = v.u;
  return (unsigned short)((u + 0x7fffu + ((u >> 16) & 1u)) >> 16);
}

// Trans ops via compiler-visible intrinsics (NOT inline asm) — R5-proven:
// the backend hazard recognizer must see v_exp_f32/v_rcp_f32.
__device__ __forceinline__ float fexp2(float x) { return __builtin_amdgcn_exp2f(x); }
__device__ __forceinline__ float frcp(float x)  { return __builtin_amdgcn_rcpf(x); }

__device__ __forceinline__ floatx4 mfma16(short8 a, short8 b, floatx4 c) {
  return __builtin_amdgcn_mfma_f32_16x16x32_bf16(a, b, c, 0, 0, 0);
}

// ---------------- Projection GEMM (R2/R5-proven, untouched) ---------------
// mode 0: Q scaled by log2(e)/8 -> [b,h,n,d]; mode 1: K -> [b,h,n,d];
// mode 2: V -> [b,h,d,n] (transposed for PV B-fragments)
constexpr int LDT = 40; // padded LDS row (bf16)

__global__ __launch_bounds__(256, 2) void proj_kernel(
    const float* __restrict__ Xq, const float* __restrict__ Xk, const float* __restrict__ Xv,
    const float* __restrict__ Wq, const float* __restrict__ Wk, const float* __restrict__ Wv,
    const float* __restrict__ bq, const float* __restrict__ bk, const float* __restrict__ bv,
    ushort_t* __restrict__ Qb, ushort_t* __restrict__ Kb, ushort_t* __restrict__ Vt)
{
  const int mode = blockIdx.z;
  const float* X    = (mode == 0) ? Xq : (mode == 1) ? Xk : Xv;
  const float* W    = (mode == 0) ? Wq : (mode == 1) ? Wk : Wv;
  const float* bias = (mode == 0) ? bq : (mode == 1) ? bk : bv;
  ushort_t* dst     = (mode == 0) ? Qb : (mode == 1) ? Kb : Vt;

  __shared__ ushort_t Asm[128 * LDT];
  __shared__ ushort_t Bsm[128 * LDT];

  const int tid = threadIdx.x, lane = tid & 63, wid = tid >> 6;
  const int m0 = blockIdx.y * 128, n0 = blockIdx.x * 128;
  const int c = lane & 15, g = lane >> 4;
  const int wm = wid & 1, wn = wid >> 1, mb = wm * 64, nb = wn * 64;

  floatx4 acc[4][4];
  #pragma unroll
  for (int i = 0; i < 4; i++)
    #pragma unroll
    for (int j = 0; j < 4; j++) acc[i][j] = floatx4{0.f, 0.f, 0.f, 0.f};

  const int ar = tid >> 1, ah = tid & 1;      // A staging: row, k-half
  const int bn = tid & 127, bh2 = tid >> 7;   // B staging: col n, k-half

  for (int k0 = 0; k0 < DM_; k0 += 32) {
    const floatx4* ap = (const floatx4*)(X + (size_t)(m0 + ar) * DM_ + k0 + ah * 16);
    floatx4 av0 = ap[0], av1 = ap[1], av2 = ap[2], av3 = ap[3];
    const float* wp = W + (size_t)(k0 + bh2 * 16) * 1024 + n0 + bn;
    float wv[16];
    #pragma unroll
    for (int j = 0; j < 16; j++) wv[j] = wp[j * 1024];

    short8 pa0, pa1, pb0, pb1;
    #pragma unroll
    for (int j = 0; j < 4; j++) {
      pa0[j] = (short)f2bf(av0[j]); pa0[4 + j] = (short)f2bf(av1[j]);
      pa1[j] = (short)f2bf(av2[j]); pa1[4 + j] = (short)f2bf(av3[j]);
    }
    #pragma unroll
    for (int j = 0; j < 8; j++) { pb0[j] = (short)f2bf(wv[j]); pb1[j] = (short)f2bf(wv[8 + j]); }

    __syncthreads();   // previous iter's fragment reads complete
    *(short8*)&Asm[ar * LDT + ah * 16]      = pa0;
    *(short8*)&Asm[ar * LDT + ah * 16 + 8]  = pa1;
    *(short8*)&Bsm[bn * LDT + bh2 * 16]     = pb0;
    *(short8*)&Bsm[bn * LDT + bh2 * 16 + 8] = pb1;
    __syncthreads();

    short8 af[4], bfr[4];
    #pragma unroll
    for (int i = 0; i < 4; i++) af[i]  = *(const short8*)&Asm[(mb + i * 16 + c) * LDT + g * 8];
    #pragma unroll
    for (int j = 0; j < 4; j++) bfr[j] = *(const short8*)&Bsm[(nb + j * 16 + c) * LDT + g * 8];
    #pragma unroll
    for (int i = 0; i < 4; i++)
      #pragma unroll
      for (int j = 0; j < 4; j++) acc[i][j] = mfma16(af[i], bfr[j], acc[i][j]);
  }

  // epilogue: C/D layout col=lane&15, row=(lane>>4)*4+reg
  #pragma unroll
  for (int j = 0; j < 4; j++) {
    const int col = n0 + nb + j * 16 + c;
    const float bv_ = bias[col];
    const int h = col >> 6, d = col & 63;
    #pragma unroll
    for (int i = 0; i < 4; i++) {
      #pragma unroll
      for (int r = 0; r < 4; r++) {
        const int row = m0 + mb + i * 16 + g * 4 + r;
        const int b = row >> 11, n = row & 2047;
        float v = acc[i][j][r] + bv_;
        if (mode == 0) {
          v *= 0.18033688011112042f;  // log2(e)/8 folded into Q
          dst[((size_t)(b * H_ + h) * NQ_ + n) * DKV_ + d] = f2bf(v);
        } else if (mode == 1) {
          dst[((size_t)(b * H_ + h) * NQ_ + n) * DKV_ + d] = f2bf(v);
        } else {
          dst[((size_t)(b * H_ + h) * DKV_ + d) * NK_ + n] = f2bf(v);
        }
      }
    }
  }
}

// ---------------- attn v3: LDS-staged K/V (dbuf), no-max flash ------------
// Block = 4 waves, 128 q-rows (32/wave). K-tile 64/iter staged in LDS shared
// by all waves; double-buffered, one barrier/iter. gp is the only global
// load in the compute body (its vmcnt wait no longer drains K/V).
// Stride 72 shorts: conflict-free for all b128 patterns here (8 dw/bank).
__global__ __launch_bounds__(256, 2) void attn_kernel(
    const ushort_t* __restrict__ Qb, const ushort_t* __restrict__ Kb,
    const ushort_t* __restrict__ Vt, const float* __restrict__ gp,
    float* __restrict__ out)
{
  __shared__ ushort_t Ks[2][64 * 72];
  __shared__ ushort_t Vs[2][64 * 72];
  __shared__ ushort_t Pl[4][32 * 72];

  const int tid = threadIdx.x, lane = tid & 63, wid = tid >> 6;
  const int c = lane & 15, g = lane >> 4;
  const int h = blockIdx.x, b = blockIdx.z;       // h fastest: gp L2 locality
  const int bh = b * H_ + h;
  const int qw = blockIdx.y * 128 + wid * 32;

  const ushort_t* Qp = Qb + (size_t)bh * NQ_ * DKV_;
  const ushort_t* Kp = Kb + (size_t)bh * NK_ * DKV_;
  const ushort_t* Vp = Vt + (size_t)bh * DKV_ * NK_;
  const float* gpp = gp + (size_t)b * NQ_ * NK_ + (size_t)qw * NK_;
  ushort_t* Pw = Pl[wid];

  // cooperative staging coords: 64 rows x 64 cols per tile, 256 threads
  const int srow = wid * 16 + (lane >> 2);        // 0..63
  const int scol = (lane & 3) * 8;                // 0/8/16/24, + half*32

  // Q fragments resident (pre-scaled by log2(e)/8)
  short8 qf[2][2];
  #pragma unroll
  for (int i = 0; i < 2; i++)
    #pragma unroll
    for (int kc = 0; kc < 2; kc++)
      qf[i][kc] = *(const short8*)&Qp[(qw + i * 16 + c) * DKV_ + kc * 32 + g * 8];

  // stage tile 0 (K rows = key idx, cols = d; V rows = d, cols = key offset)
  #pragma unroll
  for (int half = 0; half < 2; half++) {
    short8 kv = *(const short8*)&Kp[(size_t)srow * DKV_ + scol + half * 32];
    short8 vv = *(const short8*)&Vp[(size_t)srow * NK_ + scol + half * 32];
    *(short8*)&Ks[0][srow * 72 + scol + half * 32] = kv;
    *(short8*)&Vs[0][srow * 72 + scol + half * 32] = vv;
  }
  __syncthreads();

  floatx4 o[2][4];
  float l[2][4];
  #pragma unroll
  for (int i = 0; i < 2; i++) {
    #pragma unroll
    for (int jd = 0; jd < 4; jd++) o[i][jd] = floatx4{0.f, 0.f, 0.f, 0.f};
    #pragma unroll
    for (int r = 0; r < 4; r++) l[i][r] = 0.f;
  }

  for (int t = 0; t < NK_ / 64; t++) {
    const int k0 = t * 64;
    const int cur = t & 1, nxt = cur ^ 1;

    // gp gathers first (consumed after S-MFMA; issued before staging loads
    // so the staging vmcnt wait at the bottom does not gate them)
    float gpv[2][4][4];
    #pragma unroll
    for (int i = 0; i < 2; i++)
      #pragma unroll
      for (int r = 0; r < 4; r++) {
        const float* gq = gpp + (size_t)(i * 16 + g * 4 + r) * NK_ + k0 + c;
        #pragma unroll
        for (int jk = 0; jk < 4; jk++) gpv[i][jk][r] = gq[jk * 16];
      }

    // issue next tile's global loads (latency covered by whole body)
    short8 knx[2], vnx[2];
    const bool has_next = (t + 1) < NK_ / 64;
    if (has_next) {
      const int k1 = k0 + 64;
      #pragma unroll
      for (int half = 0; half < 2; half++) {
        knx[half] = *(const short8*)&Kp[(size_t)(k1 + srow) * DKV_ + scol + half * 32];
        vnx[half] = *(const short8*)&Vp[(size_t)srow * NK_ + k1 + scol + half * 32];
      }
    }

    // S = Q K^T (log2 domain), K from LDS
    floatx4 s[2][4];
    #pragma unroll
    for (int i = 0; i < 2; i++)
      #pragma unroll
      for (int jk = 0; jk < 4; jk++) s[i][jk] = floatx4{0.f, 0.f, 0.f, 0.f};
    #pragma unroll
    for (int jk = 0; jk < 4; jk++) {
      #pragma unroll
      for (int kc = 0; kc < 2; kc++) {
        short8 kf = *(const short8*)&Ks[cur][(jk * 16 + c) * 72 + kc * 32 + g * 8];
        #pragma unroll
        for (int i = 0; i < 2; i++) s[i][jk] = mfma16(qf[i][kc], kf, s[i][jk]);
      }
    }

    // p = exp2(s); per-lane l partial; gate by gp; P -> LDS (C->A transpose)
    #pragma unroll
    for (int i = 0; i < 2; i++)
      #pragma unroll
      for (int jk = 0; jk < 4; jk++)
        #pragma unroll
        for (int r = 0; r < 4; r++) {
          const float p = fexp2(s[i][jk][r]);
          l[i][r] += p;
          Pw[(i * 16 + g * 4 + r) * 72 + jk * 16 + c] = f2bf(p * gpv[i][jk][r]);
        }

    // PV: A = P rows (LDS, same-wave RAW -> lgkm waits), B = V from LDS
    #pragma unroll
    for (int kc = 0; kc < 2; kc++) {
      short8 af0 = *(const short8*)&Pw[(0 * 16 + c) * 72 + kc * 32 + g * 8];
      short8 af1 = *(const short8*)&Pw[(1 * 16 + c) * 72 + kc * 32 + g * 8];
      #pragma unroll
      for (int jd = 0; jd < 4; jd++) {
        short8 vf = *(const short8*)&Vs[cur][(jd * 16 + c) * 72 + kc * 32 + g * 8];
        o[0][jd] = mfma16(af0, vf, o[0][jd]);
        o[1][jd] = mfma16(af1, vf, o[1][jd]);
      }
    }

    // commit next tile to the other LDS buffer, then barrier
    if (has_next) {
      #pragma unroll
      for (int half = 0; half < 2; half++) {
        *(short8*)&Ks[nxt][srow * 72 + scol + half * 32] = knx[half];
        *(short8*)&Vs[nxt][srow * 72 + scol + half * 32] = vnx[half];
      }
    }
    __syncthreads();
  }

  // l-reduction across the 16 c-lanes (once per kernel)
  float invl[2][4];
  #pragma unroll
  for (int i = 0; i < 2; i++)
    #pragma unroll
    for (int r = 0; r < 4; r++) {
      float rs = l[i][r];
      rs += __shfl_xor(rs, 1);
      rs += __shfl_xor(rs, 2);
      rs += __shfl_xor(rs, 4);
      rs += __shfl_xor(rs, 8);
      invl[i][r] = frcp(rs);
    }
  #pragma unroll
  for (int i = 0; i < 2; i++)
    #pragma unroll
    for (int jd = 0; jd < 4; jd++)
      #pragma unroll
      for (int r = 0; r < 4; r++) {
        const int row = qw + i * 16 + g * 4 + r;
        out[(size_t)(b * NQ_ + row) * 1024 + h * 64 + jd * 16 + c] =
            o[i][jd][r] * invl[i][r];
      }
}

extern "C" void kernel_launch(void* const* d_in, const int* in_sizes, int n_in,
                              void* d_out, int out_size, void* d_ws, size_t ws_size,
                              hipStream_t stream) {
  const float* queries = (const float*)d_in[0];
  const float* keys    = (const float*)d_in[1];
  const float* values  = (const float*)d_in[2];
  const float* gp      = (const float*)d_in[3];
  // d_in[4] attention_mask: intentionally unused (reference discards it)
  const float* Wq = (const float*)d_in[5];
  const float* bq = (const float*)d_in[6];
  const float* Wk = (const float*)d_in[7];
  const float* bk = (const float*)d_in[8];
  const float* Wv = (const float*)d_in[9];
  const float* bv = (const float*)d_in[10];

  ushort_t* Qb = (ushort_t*)d_ws;                       // [B,H,NQ,64] bf16, pre-scaled
  ushort_t* Kb = Qb + (size_t)B_ * H_ * NQ_ * DKV_;     // [B,H,NK,64] bf16
  ushort_t* Vt = Kb + (size_t)B_ * H_ * NK_ * DKV_;     // [B,H,64,NK] bf16
  float* out = (float*)d_out;

  proj_kernel<<<dim3(8, 32, 3), 256, 0, stream>>>(
      queries, keys, values, Wq, Wk, Wv, bq, bk, bv, Qb, Kb, Vt);
  attn_kernel<<<dim3(H_, NQ_ / 128, B_), 256, 0, stream>>>(Qb, Kb, Vt, gp, out);
}

// Round 7
// 252.911 us; speedup vs baseline: 1.7123x; 1.0898x over previous
//
#include <hip/hip_runtime.h>
#include <hip/hip_bf16.h>
#include <cstdint>

typedef unsigned short ushort_t;
typedef __attribute__((ext_vector_type(8))) short short8;
typedef __attribute__((ext_vector_type(4))) float floatx4;
typedef __attribute__((ext_vector_type(4))) unsigned short ushort4_t;

#define H_   16
#define DKV_ 64
#define DM_  1024
#define B_   2
#define NQ_  2048
#define NK_  2048

// fp32 -> bf16 round-to-nearest-even
__device__ __forceinline__ unsigned short f2bf(float f) {
  union { float f; unsigned int u; } v; v.f = f;
  unsigned int u = v.u;
  return (unsigned short)((u + 0x7fffu + ((u >> 16) & 1u)) >> 16);
}

// Trans ops via compiler-visible intrinsics (NOT inline asm) — R5-proven.
__device__ __forceinline__ float fexp2(float x) { return __builtin_amdgcn_exp2f(x); }
__device__ __forceinline__ float frcp(float x)  { return __builtin_amdgcn_rcpf(x); }

__device__ __forceinline__ floatx4 mfma16(short8 a, short8 b, floatx4 c) {
  return __builtin_amdgcn_mfma_f32_16x16x32_bf16(a, b, c, 0, 0, 0);
}

// async global->LDS, 16B per lane; LDS dest = wave-uniform base + lane*16
__device__ __forceinline__ void gload_lds16(const ushort_t* g, ushort_t* l) {
  __builtin_amdgcn_global_load_lds(
      (const __attribute__((address_space(1))) void*)g,
      (__attribute__((address_space(3))) void*)l, 16, 0, 0);
}

// ---------------- cast kernels --------------------------------------------
// X: [4096,1024] fp32 -> bf16, layout preserved; 3 tensors (q,k,v)
__global__ __launch_bounds__(256) void cast_x_kernel(
    const float* __restrict__ q, const float* __restrict__ k,
    const float* __restrict__ v, ushort_t* __restrict__ dst)
{
  const int t = blockIdx.y;
  const float* src = (t == 0) ? q : (t == 1) ? k : v;
  ushort_t* d = dst + (size_t)t * 4096 * 1024;
  const int gid = blockIdx.x * 256 + threadIdx.x;   // 512 blocks -> 131072 thr
  #pragma unroll
  for (int u = 0; u < 8; u++) {
    const int i4 = u * 131072 + gid;                // 1,048,576 float4 total
    floatx4 f = ((const floatx4*)src)[i4];
    ushort4_t o;
    #pragma unroll
    for (int e = 0; e < 4; e++) o[e] = f2bf(f[e]);
    *(ushort4_t*)&d[(size_t)i4 * 4] = o;
  }
}

// W: [k=1024][n=1024] fp32 -> Wt [n][k] bf16 (transposed), 3 tensors
__global__ __launch_bounds__(256) void cast_wt_kernel(
    const float* __restrict__ Wq, const float* __restrict__ Wk,
    const float* __restrict__ Wv, ushort_t* __restrict__ WtAll)
{
  __shared__ ushort_t tile[32][33];
  const int t = blockIdx.z;
  const float* W = (t == 0) ? Wq : (t == 1) ? Wk : Wv;
  ushort_t* Wt = WtAll + (size_t)t * 1024 * 1024;
  const int n0 = blockIdx.x * 32, k0 = blockIdx.y * 32;
  const int tid = threadIdx.x, r = tid >> 3, c4 = (tid & 7) * 4;
  floatx4 f = *(const floatx4*)&W[(size_t)(k0 + r) * 1024 + n0 + c4];
  #pragma unroll
  for (int e = 0; e < 4; e++) tile[r][c4 + e] = f2bf(f[e]);
  __syncthreads();
  ushort4_t o;
  #pragma unroll
  for (int e = 0; e < 4; e++) o[e] = tile[c4 + e][r];
  *(ushort4_t*)&Wt[(size_t)(n0 + r) * 1024 + k0 + c4] = o;
}

// ---------------- proj v2: bf16 GEMM, m97-style global_load_lds -----------
// C[4096,1024] = Xbf @ W + bias; mode 0: Q*log2e/8 -> [b,h,n,d]
// mode 1: K -> [b,h,n,d]; mode 2: V -> [b,h,d,n]
__global__ __launch_bounds__(256, 2) void proj_kernel2(
    const ushort_t* __restrict__ Xbf, const ushort_t* __restrict__ WtAll,
    const float* __restrict__ bq, const float* __restrict__ bk,
    const float* __restrict__ bv,
    ushort_t* __restrict__ Qb, ushort_t* __restrict__ Kb, ushort_t* __restrict__ Vt)
{
  const int mode = blockIdx.z;
  const ushort_t* X  = Xbf  + (size_t)mode * 4096 * 1024;
  const ushort_t* Wt = WtAll + (size_t)mode * 1024 * 1024;
  const float* bias  = (mode == 0) ? bq : (mode == 1) ? bk : bv;
  ushort_t* dst      = (mode == 0) ? Qb : (mode == 1) ? Kb : Vt;

  __shared__ ushort_t SM[8192];          // SA = SM[0..4095], SB = SM[4096..]
  ushort_t* SA = SM;
  ushort_t* SB = SM + 4096;

  const int tid = threadIdx.x, lane = tid & 63, wid = tid >> 6;
  const int c = lane & 15, g = lane >> 4;
  const int m0 = blockIdx.y * 128, n0 = blockIdx.x * 128;
  const int wm = wid & 1, wn = wid >> 1, mb = wm * 64, nb = wn * 64;
  const int srow = lane >> 2;            // 0..15 staging row within 16-row chunk
  const int schunk = (lane & 3) * 8;     // element offset within 32-elem row

  floatx4 acc[4][4];
  #pragma unroll
  for (int i = 0; i < 4; i++)
    #pragma unroll
    for (int j = 0; j < 4; j++) acc[i][j] = floatx4{0.f, 0.f, 0.f, 0.f};

  for (int k0 = 0; k0 < DM_; k0 += 32) {
    __syncthreads();   // previous iteration's fragment reads complete
    #pragma unroll
    for (int u = 0; u < 2; u++) {
      const int t = wid * 2 + u;         // 16-row chunk id, 0..7
      gload_lds16(&X [(size_t)(m0 + t * 16 + srow) * 1024 + k0 + schunk], &SA[t * 512]);
      gload_lds16(&Wt[(size_t)(n0 + t * 16 + srow) * 1024 + k0 + schunk], &SB[t * 512]);
    }
    __syncthreads();   // drains vmcnt (global_load_lds) per barrier semantics

    short8 af[4], bfr[4];
    #pragma unroll
    for (int i = 0; i < 4; i++) af[i]  = *(const short8*)&SA[(mb + i * 16 + c) * 32 + g * 8];
    #pragma unroll
    for (int j = 0; j < 4; j++) bfr[j] = *(const short8*)&SB[(nb + j * 16 + c) * 32 + g * 8];
    #pragma unroll
    for (int i = 0; i < 4; i++)
      #pragma unroll
      for (int j = 0; j < 4; j++) acc[i][j] = mfma16(af[i], bfr[j], acc[i][j]);
  }

  __syncthreads();     // before reusing SM for the epilogue
  const float scale = (mode == 0) ? 0.18033688011112042f : 1.0f; // log2(e)/8
  ushort_t* EP = SM + wid * 2048;        // 4 KB per wave, disjoint regions
  const int hh = (n0 + nb) >> 6;         // wave tile covers exactly one head

  if (mode != 2) {
    // LDS layout [row=n][col=d-half], 32 cols per round; coalesced ushort4 out
    for (int jj = 0; jj < 2; jj++) {
      #pragma unroll
      for (int jt = 0; jt < 2; jt++) {
        const int j = jj * 2 + jt;
        const float bb = bias[n0 + nb + j * 16 + c];
        #pragma unroll
        for (int i = 0; i < 4; i++)
          #pragma unroll
          for (int r = 0; r < 4; r++)
            EP[(i * 16 + g * 4 + r) * 32 + jt * 16 + c] =
                f2bf((acc[i][j][r] + bb) * scale);
      }
      // in-wave LDS write->read: lgkm waits inserted by compiler
      #pragma unroll
      for (int u = 0; u < 8; u++) {
        const int rowl = u * 8 + (lane >> 3);
        ushort4_t vv = *(ushort4_t*)&EP[rowl * 32 + (lane & 7) * 4];
        const int rowg = m0 + mb + rowl;
        const int bb2 = rowg >> 11, nn = rowg & 2047;
        *(ushort4_t*)&dst[((size_t)(bb2 * H_ + hh) * NQ_ + nn) * DKV_ +
                          jj * 32 + (lane & 7) * 4] = vv;
      }
    }
  } else {
    // LDS layout [col=d][row=n] stride 72 (16B-aligned rows); b128 packed writes
    const int bb2 = (m0 + mb) >> 11, nloc = (m0 + mb) & 2047;
    for (int j = 0; j < 4; j++) {
      const float bb = bias[n0 + nb + j * 16 + c];
      #pragma unroll
      for (int i = 0; i < 4; i++) {
        ushort4_t pk;
        #pragma unroll
        for (int r = 0; r < 4; r++) pk[r] = f2bf(acc[i][j][r] + bb);
        *(ushort4_t*)&EP[c * 72 + i * 16 + g * 4] = pk;
      }
      const int d0 = j * 16;
      #pragma unroll
      for (int u = 0; u < 2; u++) {
        const int coll = u * 8 + (lane >> 3);
        short8 vv = *(const short8*)&EP[coll * 72 + (lane & 7) * 8];
        *(short8*)&dst[((size_t)(bb2 * H_ + hh) * DKV_ + d0 + coll) * NK_ +
                       nloc + (lane & 7) * 8] = vv;
      }
    }
  }
}

// ---------------- proj fallback (R2/R5-proven, fp32 inputs) ---------------
constexpr int LDT = 40;
__global__ __launch_bounds__(256, 2) void proj_kernel_fb(
    const float* __restrict__ Xq, const float* __restrict__ Xk, const float* __restrict__ Xv,
    const float* __restrict__ Wq, const float* __restrict__ Wk, const float* __restrict__ Wv,
    const float* __restrict__ bq, const float* __restrict__ bk, const float* __restrict__ bv,
    ushort_t* __restrict__ Qb, ushort_t* __restrict__ Kb, ushort_t* __restrict__ Vt)
{
  const int mode = blockIdx.z;
  const float* X    = (mode == 0) ? Xq : (mode == 1) ? Xk : Xv;
  const float* W    = (mode == 0) ? Wq : (mode == 1) ? Wk : Wv;
  const float* bias = (mode == 0) ? bq : (mode == 1) ? bk : bv;
  ushort_t* dst     = (mode == 0) ? Qb : (mode == 1) ? Kb : Vt;

  __shared__ ushort_t Asm[128 * LDT];
  __shared__ ushort_t Bsm[128 * LDT];

  const int tid = threadIdx.x, lane = tid & 63, wid = tid >> 6;
  const int m0 = blockIdx.y * 128, n0 = blockIdx.x * 128;
  const int c = lane & 15, g = lane >> 4;
  const int wm = wid & 1, wn = wid >> 1, mb = wm * 64, nb = wn * 64;

  floatx4 acc[4][4];
  #pragma unroll
  for (int i = 0; i < 4; i++)
    #pragma unroll
    for (int j = 0; j < 4; j++) acc[i][j] = floatx4{0.f, 0.f, 0.f, 0.f};

  const int ar = tid >> 1, ah = tid & 1;
  const int bn = tid & 127, bh2 = tid >> 7;

  for (int k0 = 0; k0 < DM_; k0 += 32) {
    const floatx4* ap = (const floatx4*)(X + (size_t)(m0 + ar) * DM_ + k0 + ah * 16);
    floatx4 av0 = ap[0], av1 = ap[1], av2 = ap[2], av3 = ap[3];
    const float* wp = W + (size_t)(k0 + bh2 * 16) * 1024 + n0 + bn;
    float wv[16];
    #pragma unroll
    for (int j = 0; j < 16; j++) wv[j] = wp[j * 1024];
    short8 pa0, pa1, pb0, pb1;
    #pragma unroll
    for (int j = 0; j < 4; j++) {
      pa0[j] = (short)f2bf(av0[j]); pa0[4 + j] = (short)f2bf(av1[j]);
      pa1[j] = (short)f2bf(av2[j]); pa1[4 + j] = (short)f2bf(av3[j]);
    }
    #pragma unroll
    for (int j = 0; j < 8; j++) { pb0[j] = (short)f2bf(wv[j]); pb1[j] = (short)f2bf(wv[8 + j]); }
    __syncthreads();
    *(short8*)&Asm[ar * LDT + ah * 16]      = pa0;
    *(short8*)&Asm[ar * LDT + ah * 16 + 8]  = pa1;
    *(short8*)&Bsm[bn * LDT + bh2 * 16]     = pb0;
    *(short8*)&Bsm[bn * LDT + bh2 * 16 + 8] = pb1;
    __syncthreads();
    short8 af[4], bfr[4];
    #pragma unroll
    for (int i = 0; i < 4; i++) af[i]  = *(const short8*)&Asm[(mb + i * 16 + c) * LDT + g * 8];
    #pragma unroll
    for (int j = 0; j < 4; j++) bfr[j] = *(const short8*)&Bsm[(nb + j * 16 + c) * LDT + g * 8];
    #pragma unroll
    for (int i = 0; i < 4; i++)
      #pragma unroll
      for (int j = 0; j < 4; j++) acc[i][j] = mfma16(af[i], bfr[j], acc[i][j]);
  }
  #pragma unroll
  for (int j = 0; j < 4; j++) {
    const int col = n0 + nb + j * 16 + c;
    const float bv_ = bias[col];
    const int h = col >> 6, d = col & 63;
    #pragma unroll
    for (int i = 0; i < 4; i++)
      #pragma unroll
      for (int r = 0; r < 4; r++) {
        const int row = m0 + mb + i * 16 + g * 4 + r;
        const int b = row >> 11, n = row & 2047;
        float v = acc[i][j][r] + bv_;
        if (mode == 0) {
          v *= 0.18033688011112042f;
          dst[((size_t)(b * H_ + h) * NQ_ + n) * DKV_ + d] = f2bf(v);
        } else if (mode == 1) {
          dst[((size_t)(b * H_ + h) * NQ_ + n) * DKV_ + d] = f2bf(v);
        } else {
          dst[((size_t)(b * H_ + h) * DKV_ + d) * NK_ + n] = f2bf(v);
        }
      }
  }
}

// ---------------- attn v3 (R6-proven, byte-identical) ---------------------
__global__ __launch_bounds__(256, 2) void attn_kernel(
    const ushort_t* __restrict__ Qb, const ushort_t* __restrict__ Kb,
    const ushort_t* __restrict__ Vt, const float* __restrict__ gp,
    float* __restrict__ out)
{
  __shared__ ushort_t Ks[2][64 * 72];
  __shared__ ushort_t Vs[2][64 * 72];
  __shared__ ushort_t Pl[4][32 * 72];

  const int tid = threadIdx.x, lane = tid & 63, wid = tid >> 6;
  const int c = lane & 15, g = lane >> 4;
  const int h = blockIdx.x, b = blockIdx.z;       // h fastest: gp L2 locality
  const int bh = b * H_ + h;
  const int qw = blockIdx.y * 128 + wid * 32;

  const ushort_t* Qp = Qb + (size_t)bh * NQ_ * DKV_;
  const ushort_t* Kp = Kb + (size_t)bh * NK_ * DKV_;
  const ushort_t* Vp = Vt + (size_t)bh * DKV_ * NK_;
  const float* gpp = gp + (size_t)b * NQ_ * NK_ + (size_t)qw * NK_;
  ushort_t* Pw = Pl[wid];

  const int srow = wid * 16 + (lane >> 2);        // 0..63
  const int scol = (lane & 3) * 8;                // 0/8/16/24, + half*32

  short8 qf[2][2];
  #pragma unroll
  for (int i = 0; i < 2; i++)
    #pragma unroll
    for (int kc = 0; kc < 2; kc++)
      qf[i][kc] = *(const short8*)&Qp[(qw + i * 16 + c) * DKV_ + kc * 32 + g * 8];

  #pragma unroll
  for (int half = 0; half < 2; half++) {
    short8 kv = *(const short8*)&Kp[(size_t)srow * DKV_ + scol + half * 32];
    short8 vv = *(const short8*)&Vp[(size_t)srow * NK_ + scol + half * 32];
    *(short8*)&Ks[0][srow * 72 + scol + half * 32] = kv;
    *(short8*)&Vs[0][srow * 72 + scol + half * 32] = vv;
  }
  __syncthreads();

  floatx4 o[2][4];
  float l[2][4];
  #pragma unroll
  for (int i = 0; i < 2; i++) {
    #pragma unroll
    for (int jd = 0; jd < 4; jd++) o[i][jd] = floatx4{0.f, 0.f, 0.f, 0.f};
    #pragma unroll
    for (int r = 0; r < 4; r++) l[i][r] = 0.f;
  }

  for (int t = 0; t < NK_ / 64; t++) {
    const int k0 = t * 64;
    const int cur = t & 1, nxt = cur ^ 1;

    float gpv[2][4][4];
    #pragma unroll
    for (int i = 0; i < 2; i++)
      #pragma unroll
      for (int r = 0; r < 4; r++) {
        const float* gq = gpp + (size_t)(i * 16 + g * 4 + r) * NK_ + k0 + c;
        #pragma unroll
        for (int jk = 0; jk < 4; jk++) gpv[i][jk][r] = gq[jk * 16];
      }

    short8 knx[2], vnx[2];
    const bool has_next = (t + 1) < NK_ / 64;
    if (has_next) {
      const int k1 = k0 + 64;
      #pragma unroll
      for (int half = 0; half < 2; half++) {
        knx[half] = *(const short8*)&Kp[(size_t)(k1 + srow) * DKV_ + scol + half * 32];
        vnx[half] = *(const short8*)&Vp[(size_t)srow * NK_ + k1 + scol + half * 32];
      }
    }

    floatx4 s[2][4];
    #pragma unroll
    for (int i = 0; i < 2; i++)
      #pragma unroll
      for (int jk = 0; jk < 4; jk++) s[i][jk] = floatx4{0.f, 0.f, 0.f, 0.f};
    #pragma unroll
    for (int jk = 0; jk < 4; jk++) {
      #pragma unroll
      for (int kc = 0; kc < 2; kc++) {
        short8 kf = *(const short8*)&Ks[cur][(jk * 16 + c) * 72 + kc * 32 + g * 8];
        #pragma unroll
        for (int i = 0; i < 2; i++) s[i][jk] = mfma16(qf[i][kc], kf, s[i][jk]);
      }
    }

    #pragma unroll
    for (int i = 0; i < 2; i++)
      #pragma unroll
      for (int jk = 0; jk < 4; jk++)
        #pragma unroll
        for (int r = 0; r < 4; r++) {
          const float p = fexp2(s[i][jk][r]);
          l[i][r] += p;
          Pw[(i * 16 + g * 4 + r) * 72 + jk * 16 + c] = f2bf(p * gpv[i][jk][r]);
        }

    #pragma unroll
    for (int kc = 0; kc < 2; kc++) {
      short8 af0 = *(const short8*)&Pw[(0 * 16 + c) * 72 + kc * 32 + g * 8];
      short8 af1 = *(const short8*)&Pw[(1 * 16 + c) * 72 + kc * 32 + g * 8];
      #pragma unroll
      for (int jd = 0; jd < 4; jd++) {
        short8 vf = *(const short8*)&Vs[cur][(jd * 16 + c) * 72 + kc * 32 + g * 8];
        o[0][jd] = mfma16(af0, vf, o[0][jd]);
        o[1][jd] = mfma16(af1, vf, o[1][jd]);
      }
    }

    if (has_next) {
      #pragma unroll
      for (int half = 0; half < 2; half++) {
        *(short8*)&Ks[nxt][srow * 72 + scol + half * 32] = knx[half];
        *(short8*)&Vs[nxt][srow * 72 + scol + half * 32] = vnx[half];
      }
    }
    __syncthreads();
  }

  float invl[2][4];
  #pragma unroll
  for (int i = 0; i < 2; i++)
    #pragma unroll
    for (int r = 0; r < 4; r++) {
      float rs = l[i][r];
      rs += __shfl_xor(rs, 1);
      rs += __shfl_xor(rs, 2);
      rs += __shfl_xor(rs, 4);
      rs += __shfl_xor(rs, 8);
      invl[i][r] = frcp(rs);
    }
  #pragma unroll
  for (int i = 0; i < 2; i++)
    #pragma unroll
    for (int jd = 0; jd < 4; jd++)
      #pragma unroll
      for (int r = 0; r < 4; r++) {
        const int row = qw + i * 16 + g * 4 + r;
        out[(size_t)(b * NQ_ + row) * 1024 + h * 64 + jd * 16 + c] =
            o[i][jd][r] * invl[i][r];
      }
}

extern "C" void kernel_launch(void* const* d_in, const int* in_sizes, int n_in,
                              void* d_out, int out_size, void* d_ws, size_t ws_size,
                              hipStream_t stream) {
  const float* queries = (const float*)d_in[0];
  const float* keys    = (const float*)d_in[1];
  const float* values  = (const float*)d_in[2];
  const float* gp      = (const float*)d_in[3];
  // d_in[4] attention_mask: intentionally unused (reference discards it)
  const float* Wq = (const float*)d_in[5];
  const float* bq = (const float*)d_in[6];
  const float* Wk = (const float*)d_in[7];
  const float* bk = (const float*)d_in[8];
  const float* Wv = (const float*)d_in[9];
  const float* bv = (const float*)d_in[10];

  const size_t SZ_QKV = (size_t)3 * B_ * H_ * NQ_ * DKV_;  // shorts
  const size_t SZ_X   = (size_t)3 * 4096 * 1024;
  const size_t SZ_W   = (size_t)3 * 1024 * 1024;
  const size_t NEED   = (SZ_QKV + SZ_X + SZ_W) * sizeof(ushort_t);

  ushort_t* Qb = (ushort_t*)d_ws;                       // [B,H,NQ,64] bf16, pre-scaled
  ushort_t* Kb = Qb + (size_t)B_ * H_ * NQ_ * DKV_;     // [B,H,NK,64] bf16
  ushort_t* Vt = Kb + (size_t)B_ * H_ * NK_ * DKV_;     // [B,H,64,NK] bf16
  float* out = (float*)d_out;

  if (ws_size >= NEED) {
    ushort_t* Xbf = Qb + SZ_QKV;
    ushort_t* Wt  = Xbf + SZ_X;
    cast_x_kernel<<<dim3(512, 3), 256, 0, stream>>>(queries, keys, values, Xbf);
    cast_wt_kernel<<<dim3(32, 32, 3), 256, 0, stream>>>(Wq, Wk, Wv, Wt);
    proj_kernel2<<<dim3(8, 32, 3), 256, 0, stream>>>(
        Xbf, Wt, bq, bk, bv, Qb, Kb, Vt);
  } else {
    proj_kernel_fb<<<dim3(8, 32, 3), 256, 0, stream>>>(
        queries, keys, values, Wq, Wk, Wv, bq, bk, bv, Qb, Kb, Vt);
  }
  attn_kernel<<<dim3(H_, NQ_ / 128, B_), 256, 0, stream>>>(Qb, Kb, Vt, gp, out);
}

// Round 8
// 245.594 us; speedup vs baseline: 1.7633x; 1.0298x over previous
//
#include <hip/hip_runtime.h>
#include <hip/hip_bf16.h>
#include <cstdint>

typedef unsigned short ushort_t;
typedef __attribute__((ext_vector_type(8))) short short8;
typedef __attribute__((ext_vector_type(4))) float floatx4;
typedef __attribute__((ext_vector_type(4))) unsigned short ushort4_t;

#define H_   16
#define DKV_ 64
#define DM_  1024
#define B_   2
#define NQ_  2048
#define NK_  2048

// fp32 -> bf16 round-to-nearest-even
__device__ __forceinline__ unsigned short f2bf(float f) {
  union { float f; unsigned int u; } v; v.f = f;
  unsigned int u = v.u;
  return (unsigned short)((u + 0x7fffu + ((u >> 16) & 1u)) >> 16);
}

// Trans ops via compiler-visible intrinsics (NOT inline asm) — R5-proven.
__device__ __forceinline__ float fexp2(float x) { return __builtin_amdgcn_exp2f(x); }
__device__ __forceinline__ float frcp(float x)  { return __builtin_amdgcn_rcpf(x); }

__device__ __forceinline__ floatx4 mfma16(short8 a, short8 b, floatx4 c) {
  return __builtin_amdgcn_mfma_f32_16x16x32_bf16(a, b, c, 0, 0, 0);
}

// async global->LDS, 16B per lane; LDS dest = wave-uniform base + lane*16
__device__ __forceinline__ void gload_lds16(const ushort_t* g, ushort_t* l) {
  __builtin_amdgcn_global_load_lds(
      (const __attribute__((address_space(1))) void*)g,
      (__attribute__((address_space(3))) void*)l, 16, 0, 0);
}

// ---------------- cast kernels (R7-proven) --------------------------------
__global__ __launch_bounds__(256) void cast_x_kernel(
    const float* __restrict__ q, const float* __restrict__ k,
    const float* __restrict__ v, ushort_t* __restrict__ dst)
{
  const int t = blockIdx.y;
  const float* src = (t == 0) ? q : (t == 1) ? k : v;
  ushort_t* d = dst + (size_t)t * 4096 * 1024;
  const int gid = blockIdx.x * 256 + threadIdx.x;
  #pragma unroll
  for (int u = 0; u < 8; u++) {
    const int i4 = u * 131072 + gid;
    floatx4 f = ((const floatx4*)src)[i4];
    ushort4_t o;
    #pragma unroll
    for (int e = 0; e < 4; e++) o[e] = f2bf(f[e]);
    *(ushort4_t*)&d[(size_t)i4 * 4] = o;
  }
}

__global__ __launch_bounds__(256) void cast_wt_kernel(
    const float* __restrict__ Wq, const float* __restrict__ Wk,
    const float* __restrict__ Wv, ushort_t* __restrict__ WtAll)
{
  __shared__ ushort_t tile[32][33];
  const int t = blockIdx.z;
  const float* W = (t == 0) ? Wq : (t == 1) ? Wk : Wv;
  ushort_t* Wt = WtAll + (size_t)t * 1024 * 1024;
  const int n0 = blockIdx.x * 32, k0 = blockIdx.y * 32;
  const int tid = threadIdx.x, r = tid >> 3, c4 = (tid & 7) * 4;
  floatx4 f = *(const floatx4*)&W[(size_t)(k0 + r) * 1024 + n0 + c4];
  #pragma unroll
  for (int e = 0; e < 4; e++) tile[r][c4 + e] = f2bf(f[e]);
  __syncthreads();
  ushort4_t o;
  #pragma unroll
  for (int e = 0; e < 4; e++) o[e] = tile[c4 + e][r];
  *(ushort4_t*)&Wt[(size_t)(n0 + r) * 1024 + k0 + c4] = o;
}

// ---------------- proj v2 (R7-proven, byte-identical) ---------------------
__global__ __launch_bounds__(256, 2) void proj_kernel2(
    const ushort_t* __restrict__ Xbf, const ushort_t* __restrict__ WtAll,
    const float* __restrict__ bq, const float* __restrict__ bk,
    const float* __restrict__ bv,
    ushort_t* __restrict__ Qb, ushort_t* __restrict__ Kb, ushort_t* __restrict__ Vt)
{
  const int mode = blockIdx.z;
  const ushort_t* X  = Xbf  + (size_t)mode * 4096 * 1024;
  const ushort_t* Wt = WtAll + (size_t)mode * 1024 * 1024;
  const float* bias  = (mode == 0) ? bq : (mode == 1) ? bk : bv;
  ushort_t* dst      = (mode == 0) ? Qb : (mode == 1) ? Kb : Vt;

  __shared__ ushort_t SM[8192];
  ushort_t* SA = SM;
  ushort_t* SB = SM + 4096;

  const int tid = threadIdx.x, lane = tid & 63, wid = tid >> 6;
  const int c = lane & 15, g = lane >> 4;
  const int m0 = blockIdx.y * 128, n0 = blockIdx.x * 128;
  const int wm = wid & 1, wn = wid >> 1, mb = wm * 64, nb = wn * 64;
  const int srow = lane >> 2;
  const int schunk = (lane & 3) * 8;

  floatx4 acc[4][4];
  #pragma unroll
  for (int i = 0; i < 4; i++)
    #pragma unroll
    for (int j = 0; j < 4; j++) acc[i][j] = floatx4{0.f, 0.f, 0.f, 0.f};

  for (int k0 = 0; k0 < DM_; k0 += 32) {
    __syncthreads();
    #pragma unroll
    for (int u = 0; u < 2; u++) {
      const int t = wid * 2 + u;
      gload_lds16(&X [(size_t)(m0 + t * 16 + srow) * 1024 + k0 + schunk], &SA[t * 512]);
      gload_lds16(&Wt[(size_t)(n0 + t * 16 + srow) * 1024 + k0 + schunk], &SB[t * 512]);
    }
    __syncthreads();

    short8 af[4], bfr[4];
    #pragma unroll
    for (int i = 0; i < 4; i++) af[i]  = *(const short8*)&SA[(mb + i * 16 + c) * 32 + g * 8];
    #pragma unroll
    for (int j = 0; j < 4; j++) bfr[j] = *(const short8*)&SB[(nb + j * 16 + c) * 32 + g * 8];
    #pragma unroll
    for (int i = 0; i < 4; i++)
      #pragma unroll
      for (int j = 0; j < 4; j++) acc[i][j] = mfma16(af[i], bfr[j], acc[i][j]);
  }

  __syncthreads();
  const float scale = (mode == 0) ? 0.18033688011112042f : 1.0f;
  ushort_t* EP = SM + wid * 2048;
  const int hh = (n0 + nb) >> 6;

  if (mode != 2) {
    for (int jj = 0; jj < 2; jj++) {
      #pragma unroll
      for (int jt = 0; jt < 2; jt++) {
        const int j = jj * 2 + jt;
        const float bb = bias[n0 + nb + j * 16 + c];
        #pragma unroll
        for (int i = 0; i < 4; i++)
          #pragma unroll
          for (int r = 0; r < 4; r++)
            EP[(i * 16 + g * 4 + r) * 32 + jt * 16 + c] =
                f2bf((acc[i][j][r] + bb) * scale);
      }
      #pragma unroll
      for (int u = 0; u < 8; u++) {
        const int rowl = u * 8 + (lane >> 3);
        ushort4_t vv = *(ushort4_t*)&EP[rowl * 32 + (lane & 7) * 4];
        const int rowg = m0 + mb + rowl;
        const int bb2 = rowg >> 11, nn = rowg & 2047;
        *(ushort4_t*)&dst[((size_t)(bb2 * H_ + hh) * NQ_ + nn) * DKV_ +
                          jj * 32 + (lane & 7) * 4] = vv;
      }
    }
  } else {
    const int bb2 = (m0 + mb) >> 11, nloc = (m0 + mb) & 2047;
    for (int j = 0; j < 4; j++) {
      const float bb = bias[n0 + nb + j * 16 + c];
      #pragma unroll
      for (int i = 0; i < 4; i++) {
        ushort4_t pk;
        #pragma unroll
        for (int r = 0; r < 4; r++) pk[r] = f2bf(acc[i][j][r] + bb);
        *(ushort4_t*)&EP[c * 72 + i * 16 + g * 4] = pk;
      }
      const int d0 = j * 16;
      #pragma unroll
      for (int u = 0; u < 2; u++) {
        const int coll = u * 8 + (lane >> 3);
        short8 vv = *(const short8*)&EP[coll * 72 + (lane & 7) * 8];
        *(short8*)&dst[((size_t)(bb2 * H_ + hh) * DKV_ + d0 + coll) * NK_ +
                       nloc + (lane & 7) * 8] = vv;
      }
    }
  }
}

// ---------------- proj fallback (R2/R5-proven) ----------------------------
constexpr int LDT = 40;
__global__ __launch_bounds__(256, 2) void proj_kernel_fb(
    const float* __restrict__ Xq, const float* __restrict__ Xk, const float* __restrict__ Xv,
    const float* __restrict__ Wq, const float* __restrict__ Wk, const float* __restrict__ Wv,
    const float* __restrict__ bq, const float* __restrict__ bk, const float* __restrict__ bv,
    ushort_t* __restrict__ Qb, ushort_t* __restrict__ Kb, ushort_t* __restrict__ Vt)
{
  const int mode = blockIdx.z;
  const float* X    = (mode == 0) ? Xq : (mode == 1) ? Xk : Xv;
  const float* W    = (mode == 0) ? Wq : (mode == 1) ? Wk : Wv;
  const float* bias = (mode == 0) ? bq : (mode == 1) ? bk : bv;
  ushort_t* dst     = (mode == 0) ? Qb : (mode == 1) ? Kb : Vt;

  __shared__ ushort_t Asm[128 * LDT];
  __shared__ ushort_t Bsm[128 * LDT];

  const int tid = threadIdx.x, lane = tid & 63, wid = tid >> 6;
  const int m0 = blockIdx.y * 128, n0 = blockIdx.x * 128;
  const int c = lane & 15, g = lane >> 4;
  const int wm = wid & 1, wn = wid >> 1, mb = wm * 64, nb = wn * 64;

  floatx4 acc[4][4];
  #pragma unroll
  for (int i = 0; i < 4; i++)
    #pragma unroll
    for (int j = 0; j < 4; j++) acc[i][j] = floatx4{0.f, 0.f, 0.f, 0.f};

  const int ar = tid >> 1, ah = tid & 1;
  const int bn = tid & 127, bh2 = tid >> 7;

  for (int k0 = 0; k0 < DM_; k0 += 32) {
    const floatx4* ap = (const floatx4*)(X + (size_t)(m0 + ar) * DM_ + k0 + ah * 16);
    floatx4 av0 = ap[0], av1 = ap[1], av2 = ap[2], av3 = ap[3];
    const float* wp = W + (size_t)(k0 + bh2 * 16) * 1024 + n0 + bn;
    float wv[16];
    #pragma unroll
    for (int j = 0; j < 16; j++) wv[j] = wp[j * 1024];
    short8 pa0, pa1, pb0, pb1;
    #pragma unroll
    for (int j = 0; j < 4; j++) {
      pa0[j] = (short)f2bf(av0[j]); pa0[4 + j] = (short)f2bf(av1[j]);
      pa1[j] = (short)f2bf(av2[j]); pa1[4 + j] = (short)f2bf(av3[j]);
    }
    #pragma unroll
    for (int j = 0; j < 8; j++) { pb0[j] = (short)f2bf(wv[j]); pb1[j] = (short)f2bf(wv[8 + j]); }
    __syncthreads();
    *(short8*)&Asm[ar * LDT + ah * 16]      = pa0;
    *(short8*)&Asm[ar * LDT + ah * 16 + 8]  = pa1;
    *(short8*)&Bsm[bn * LDT + bh2 * 16]     = pb0;
    *(short8*)&Bsm[bn * LDT + bh2 * 16 + 8] = pb1;
    __syncthreads();
    short8 af[4], bfr[4];
    #pragma unroll
    for (int i = 0; i < 4; i++) af[i]  = *(const short8*)&Asm[(mb + i * 16 + c) * LDT + g * 8];
    #pragma unroll
    for (int j = 0; j < 4; j++) bfr[j] = *(const short8*)&Bsm[(nb + j * 16 + c) * LDT + g * 8];
    #pragma unroll
    for (int i = 0; i < 4; i++)
      #pragma unroll
      for (int j = 0; j < 4; j++) acc[i][j] = mfma16(af[i], bfr[j], acc[i][j]);
  }
  #pragma unroll
  for (int j = 0; j < 4; j++) {
    const int col = n0 + nb + j * 16 + c;
    const float bv_ = bias[col];
    const int h = col >> 6, d = col & 63;
    #pragma unroll
    for (int i = 0; i < 4; i++)
      #pragma unroll
      for (int r = 0; r < 4; r++) {
        const int row = m0 + mb + i * 16 + g * 4 + r;
        const int b = row >> 11, n = row & 2047;
        float v = acc[i][j][r] + bv_;
        if (mode == 0) {
          v *= 0.18033688011112042f;
          dst[((size_t)(b * H_ + h) * NQ_ + n) * DKV_ + d] = f2bf(v);
        } else if (mode == 1) {
          dst[((size_t)(b * H_ + h) * NQ_ + n) * DKV_ + d] = f2bf(v);
        } else {
          dst[((size_t)(b * H_ + h) * DKV_ + d) * NK_ + n] = f2bf(v);
        }
      }
  }
}

// ---------------- attn v4: 8 waves/block (16 q/wave), swizzled P ----------
// Grid 512 blocks x 512 thr -> 16 waves/CU (2x v3 TLP). K/V dbuf identical
// to v3. P tile per wave: 16x64 stride 72 with XOR swizzle on 16-short
// granules: phys_col = col ^ (((row>>3)&1)<<4) -> conflict-free b16 writes
// (per-instruction the 4 g-groups hit disjoint 8-bank windows), b128 reads
// stay 16B-aligned and bank-balanced.
__global__ __launch_bounds__(512, 4) void attn_kernel(
    const ushort_t* __restrict__ Qb, const ushort_t* __restrict__ Kb,
    const ushort_t* __restrict__ Vt, const float* __restrict__ gp,
    float* __restrict__ out)
{
  __shared__ ushort_t Ks[2][64 * 72];
  __shared__ ushort_t Vs[2][64 * 72];
  __shared__ ushort_t Pl[8][16 * 72];

  const int tid = threadIdx.x, lane = tid & 63, wid = tid >> 6;  // wid 0..7
  const int c = lane & 15, g = lane >> 4;
  const int h = blockIdx.x, b = blockIdx.z;       // h fastest: gp L2 locality
  const int bh = b * H_ + h;
  const int qw = blockIdx.y * 128 + wid * 16;

  const ushort_t* Qp = Qb + (size_t)bh * NQ_ * DKV_;
  const ushort_t* Kp = Kb + (size_t)bh * NK_ * DKV_;
  const ushort_t* Vp = Vt + (size_t)bh * DKV_ * NK_;
  const float* gpp = gp + (size_t)b * NQ_ * NK_ + (size_t)qw * NK_;
  ushort_t* Pw = Pl[wid];

  const int gx16 = (g >> 1) << 4;                 // write-side granule XOR
  const int prd  = g ^ (((c >> 3) & 1) << 1);     // read-side swizzled g

  // cooperative staging: 512 threads cover 64x64, 1 chunk each for K and V
  const int srow = tid >> 3;                      // 0..63
  const int scol = (tid & 7) * 8;                 // 0..56

  // Q fragments resident (pre-scaled by log2(e)/8)
  short8 qf[2];
  #pragma unroll
  for (int kc = 0; kc < 2; kc++)
    qf[kc] = *(const short8*)&Qp[(qw + c) * DKV_ + kc * 32 + g * 8];

  // stage tile 0
  *(short8*)&Ks[0][srow * 72 + scol] = *(const short8*)&Kp[(size_t)srow * DKV_ + scol];
  *(short8*)&Vs[0][srow * 72 + scol] = *(const short8*)&Vp[(size_t)srow * NK_ + scol];
  __syncthreads();

  floatx4 o[4];
  float l[4];
  #pragma unroll
  for (int jd = 0; jd < 4; jd++) o[jd] = floatx4{0.f, 0.f, 0.f, 0.f};
  #pragma unroll
  for (int r = 0; r < 4; r++) l[r] = 0.f;

  for (int t = 0; t < NK_ / 64; t++) {
    const int k0 = t * 64;
    const int cur = t & 1, nxt = cur ^ 1;

    // gp gathers first (consumed after S-MFMA)
    float gpv[4][4];
    #pragma unroll
    for (int r = 0; r < 4; r++) {
      const float* gq = gpp + (size_t)(g * 4 + r) * NK_ + k0 + c;
      #pragma unroll
      for (int jk = 0; jk < 4; jk++) gpv[jk][r] = gq[jk * 16];
    }

    // issue next tile's staging loads (latency covered by whole body)
    short8 knx, vnx;
    const bool has_next = (t + 1) < NK_ / 64;
    if (has_next) {
      const int k1 = k0 + 64;
      knx = *(const short8*)&Kp[(size_t)(k1 + srow) * DKV_ + scol];
      vnx = *(const short8*)&Vp[(size_t)srow * NK_ + k1 + scol];
    }

    // S = Q K^T (log2 domain), K from LDS
    floatx4 s[4];
    #pragma unroll
    for (int jk = 0; jk < 4; jk++) s[jk] = floatx4{0.f, 0.f, 0.f, 0.f};
    #pragma unroll
    for (int jk = 0; jk < 4; jk++)
      #pragma unroll
      for (int kc = 0; kc < 2; kc++) {
        short8 kf = *(const short8*)&Ks[cur][(jk * 16 + c) * 72 + kc * 32 + g * 8];
        s[jk] = mfma16(qf[kc], kf, s[jk]);
      }

    // p = exp2(s); per-lane l; gate by gp; P -> LDS (swizzled C->A transpose)
    #pragma unroll
    for (int jk = 0; jk < 4; jk++) {
      const int colw = (jk << 4) ^ gx16;          // phys col base for this jk
      #pragma unroll
      for (int r = 0; r < 4; r++) {
        const float p = fexp2(s[jk][r]);
        l[r] += p;
        Pw[(g * 4 + r) * 72 + colw + c] = f2bf(p * gpv[jk][r]);
      }
    }

    // PV: A = P rows (swizzled read), B = V from LDS
    #pragma unroll
    for (int kc = 0; kc < 2; kc++) {
      short8 af = *(const short8*)&Pw[c * 72 + kc * 32 + prd * 8];
      #pragma unroll
      for (int jd = 0; jd < 4; jd++) {
        short8 vf = *(const short8*)&Vs[cur][(jd * 16 + c) * 72 + kc * 32 + g * 8];
        o[jd] = mfma16(af, vf, o[jd]);
      }
    }

    // commit next tile, then barrier
    if (has_next) {
      *(short8*)&Ks[nxt][srow * 72 + scol] = knx;
      *(short8*)&Vs[nxt][srow * 72 + scol] = vnx;
    }
    __syncthreads();
  }

  // l-reduction across the 16 c-lanes (once per kernel)
  float invl[4];
  #pragma unroll
  for (int r = 0; r < 4; r++) {
    float rs = l[r];
    rs += __shfl_xor(rs, 1);
    rs += __shfl_xor(rs, 2);
    rs += __shfl_xor(rs, 4);
    rs += __shfl_xor(rs, 8);
    invl[r] = frcp(rs);
  }
  #pragma unroll
  for (int jd = 0; jd < 4; jd++)
    #pragma unroll
    for (int r = 0; r < 4; r++) {
      const int row = qw + g * 4 + r;
      out[(size_t)(b * NQ_ + row) * 1024 + h * 64 + jd * 16 + c] =
          o[jd][r] * invl[r];
    }
}

extern "C" void kernel_launch(void* const* d_in, const int* in_sizes, int n_in,
                              void* d_out, int out_size, void* d_ws, size_t ws_size,
                              hipStream_t stream) {
  const float* queries = (const float*)d_in[0];
  const float* keys    = (const float*)d_in[1];
  const float* values  = (const float*)d_in[2];
  const float* gp      = (const float*)d_in[3];
  // d_in[4] attention_mask: intentionally unused (reference discards it)
  const float* Wq = (const float*)d_in[5];
  const float* bq = (const float*)d_in[6];
  const float* Wk = (const float*)d_in[7];
  const float* bk = (const float*)d_in[8];
  const float* Wv = (const float*)d_in[9];
  const float* bv = (const float*)d_in[10];

  const size_t SZ_QKV = (size_t)3 * B_ * H_ * NQ_ * DKV_;  // shorts
  const size_t SZ_X   = (size_t)3 * 4096 * 1024;
  const size_t SZ_W   = (size_t)3 * 1024 * 1024;
  const size_t NEED   = (SZ_QKV + SZ_X + SZ_W) * sizeof(ushort_t);

  ushort_t* Qb = (ushort_t*)d_ws;                       // [B,H,NQ,64] bf16, pre-scaled
  ushort_t* Kb = Qb + (size_t)B_ * H_ * NQ_ * DKV_;     // [B,H,NK,64] bf16
  ushort_t* Vt = Kb + (size_t)B_ * H_ * NK_ * DKV_;     // [B,H,64,NK] bf16
  float* out = (float*)d_out;

  if (ws_size >= NEED) {
    ushort_t* Xbf = Qb + SZ_QKV;
    ushort_t* Wt  = Xbf + SZ_X;
    cast_x_kernel<<<dim3(512, 3), 256, 0, stream>>>(queries, keys, values, Xbf);
    cast_wt_kernel<<<dim3(32, 32, 3), 256, 0, stream>>>(Wq, Wk, Wv, Wt);
    proj_kernel2<<<dim3(8, 32, 3), 256, 0, stream>>>(
        Xbf, Wt, bq, bk, bv, Qb, Kb, Vt);
  } else {
    proj_kernel_fb<<<dim3(8, 32, 3), 256, 0, stream>>>(
        queries, keys, values, Wq, Wk, Wv, bq, bk, bv, Qb, Kb, Vt);
  }
  attn_kernel<<<dim3(H_, NQ_ / 128, B_), 512, 0, stream>>>(Qb, Kb, Vt, gp, out);
}